// Round 2
// baseline (56.686 us; speedup 1.0000x reference)
//
#include <hip/hip_runtime.h>
#include <hip/hip_bf16.h>

typedef __attribute__((ext_vector_type(8))) short short8;   // bf16x8 MFMA operand
typedef __attribute__((ext_vector_type(4))) float floatx4;  // f32x4 MFMA accumulator

#define LOG2E 1.4426950408889634f

__device__ __forceinline__ unsigned short f2bf(float f) {
  unsigned int u = __float_as_uint(f);
  u += 0x7FFFu + ((u >> 16) & 1u);   // RNE
  return (unsigned short)(u >> 16);
}

__device__ __forceinline__ unsigned int pk2(float lo, float hi) {
  __hip_bfloat162 h = __float22bfloat162_rn(make_float2(lo, hi)); // v_cvt_pk_bf16_f32
  unsigned int u;
  __builtin_memcpy(&u, &h, 4);
  return u;
}

__device__ __forceinline__ short8 pack8(float4 a, float4 b) {
  union { unsigned int u[4]; short8 s; } r;
  r.u[0] = pk2(a.x, a.y);
  r.u[1] = pk2(a.z, a.w);
  r.u[2] = pk2(b.x, b.y);
  r.u[3] = pk2(b.z, b.w);
  return r.s;
}

// ---------------- prep kernel ----------------
// ws layout (bytes):
//   Wp    [384][256] bf16 @ 0        (n' = d*64 + t, pre-scaled by -log2e)
//   fcw   [256][64]  bf16 @ 196608
//   coefg [64][64]   f32  @ 229376   (monomial-basis tree coeffs, BN folded)
//   b1    [384]      f32  @ 245760   (n'-permuted, pre-scaled by -log2e)
__global__ void prep_kernel(const float* __restrict__ W_dec,
                            const float* __restrict__ b_dec,
                            const float* __restrict__ leaf,
                            const float* __restrict__ bn_gamma,
                            const float* __restrict__ bn_beta,
                            const float* __restrict__ bn_mean,
                            const float* __restrict__ bn_var,
                            const float* __restrict__ fc_w,
                            unsigned short* __restrict__ Wp,
                            unsigned short* __restrict__ fcw,
                            float* __restrict__ coefg,
                            float* __restrict__ b1)
{
  int idx = (int)blockIdx.x * 256 + (int)threadIdx.x;
  if (idx < 384 * 256) {
    int np = idx >> 8, k = idx & 255;
    int d = np >> 6, t = np & 63;
    Wp[idx] = f2bf(-LOG2E * W_dec[(t * 6 + d) * 256 + k]);
    return;
  }
  idx -= 384 * 256;
  if (idx < 256 * 64) { fcw[idx] = f2bf(fc_w[idx]); return; }
  idx -= 256 * 64;
  if (idx < 64) {
    // Mobius transform: leaf values -> monomial coefficients over (dec5..dec0).
    // leaf-index bit p corresponds to depth (5-p); butterfly axis-by-axis.
    const int t = idx;
    float c[64];
    #pragma unroll
    for (int i = 0; i < 64; ++i) c[i] = leaf[t * 64 + i];
    #pragma unroll
    for (int p = 0; p < 6; ++p) {
      const int s = 1 << p;
      #pragma unroll
      for (int i = 0; i < 64; ++i)
        if ((i & s) == 0) c[i + s] -= c[i];
    }
    // fold BN affine: out = f*sbv + obv
    float sbv = bn_gamma[t] * rsqrtf(bn_var[t] + 1e-5f);
    float obv = bn_beta[t] - bn_mean[t] * sbv;
    #pragma unroll
    for (int i = 0; i < 64; ++i) c[i] *= sbv;
    c[0] += obv;
    #pragma unroll
    for (int i = 0; i < 64; ++i) coefg[t * 64 + i] = c[i];
    return;
  }
  idx -= 64;
  if (idx < 384) {
    int t = idx / 6, d = idx % 6;
    b1[d * 64 + t] = -LOG2E * b_dec[idx];
  }
}

// ---------------- main fused kernel ----------------
// grid 1024 x 256 threads; BM=32 rows/block; 4 waves, wave w owns trees [16w,16w+16)
// A fragments read directly from global x (f32) and packed to bf16 in registers.
__global__ __launch_bounds__(256, 4)
void node_main(const float* __restrict__ x,
               const unsigned short* __restrict__ Wp,
               const unsigned short* __restrict__ fcw,
               const float* __restrict__ coefg,
               const float* __restrict__ b1g,
               const float* __restrict__ fc_b,
               float* __restrict__ out)
{
  __shared__ float coef_lds[64][68];          // 17.4 KB, +4 pad
  __shared__ unsigned short A2_lds[32][72];   // 4.6 KB, +8 pad
  __shared__ float b1_lds[384];
  __shared__ float fcb_lds[256];

  const int tid  = (int)threadIdx.x;
  const int lane = tid & 63;
  const int w    = tid >> 6;      // wave 0..3
  const int tcol = lane & 15;
  const int g    = lane >> 4;
  const int r0   = (int)blockIdx.x * 32;

  // ---- stage small tables (no barrier needed until phase 2) ----
  #pragma unroll
  for (int i = 0; i < 4; ++i) {
    int f = tid + 256 * i;          // float4 index 0..1023
    int t = f >> 4, c4 = f & 15;
    *(float4*)&coef_lds[t][c4 * 4] = ((const float4*)coefg)[f];
  }
  b1_lds[tid] = b1g[tid];
  if (tid < 128) b1_lds[256 + tid] = b1g[256 + tid];
  fcb_lds[tid] = fc_b[tid];

  // ---- GEMM1: acc[rt][d] = x(32x256) @ Wp-slice; A from global f32 -> bf16 regs ----
  floatx4 acc[2][6];
  #pragma unroll
  for (int rt = 0; rt < 2; ++rt)
    #pragma unroll
    for (int d = 0; d < 6; ++d) { acc[rt][d][0]=0.f; acc[rt][d][1]=0.f; acc[rt][d][2]=0.f; acc[rt][d][3]=0.f; }

  const unsigned short* Bb = Wp + (size_t)(w * 16 + tcol) * 256 + g * 8;
  const float* Ab = x + (size_t)(r0 + tcol) * 256 + g * 8;

  #pragma unroll 2
  for (int kp = 0; kp < 8; ++kp) {
    short8 b[6];
    #pragma unroll
    for (int d = 0; d < 6; ++d) b[d] = *(const short8*)(Bb + d * 16384 + kp * 32);
    short8 a[2];
    #pragma unroll
    for (int rt = 0; rt < 2; ++rt) {
      const float* p = Ab + rt * 16 * 256 + kp * 32;
      float4 v0 = *(const float4*)p;
      float4 v1 = *(const float4*)(p + 4);
      a[rt] = pack8(v0, v1);
    }
    #pragma unroll
    for (int d = 0; d < 6; ++d)
      #pragma unroll
      for (int rt = 0; rt < 2; ++rt)
        acc[rt][d] = __builtin_amdgcn_mfma_f32_16x16x32_bf16(a[rt], b[d], acc[rt][d], 0, 0, 0);
  }
  __syncthreads();   // coef_lds / b1_lds ready

  // ---- phase 2: sigmoid + monomial-basis tree eval (63 fma), BN pre-folded ----
  const int tree = w * 16 + tcol;   // lane's tree; its 8 rows: rt*16 + g*4 + j
  float bp[6];
  #pragma unroll
  for (int d = 0; d < 6; ++d) bp[d] = b1_lds[d * 64 + tree];

  #pragma unroll
  for (int rt = 0; rt < 2; ++rt)
    #pragma unroll
    for (int d = 0; d < 6; ++d)
      #pragma unroll
      for (int j = 0; j < 4; ++j) {
        float z = acc[rt][d][j] + bp[d];
        acc[rt][d][j] = __builtin_amdgcn_rcpf(1.0f + __builtin_amdgcn_exp2f(z));
      }

  float L[32], resLo[8];
  #pragma unroll
  for (int c = 0; c < 8; ++c) {
    float4 v = *(const float4*)&coef_lds[tree][c * 4];
    L[c*4+0] = v.x; L[c*4+1] = v.y; L[c*4+2] = v.z; L[c*4+3] = v.w;
  }
  #pragma unroll
  for (int rt = 0; rt < 2; ++rt)
    #pragma unroll
    for (int j = 0; j < 4; ++j) {
      float u[16];
      const float d5 = acc[rt][5][j];
      #pragma unroll
      for (int i = 0; i < 16; ++i) u[i] = fmaf(d5, L[2*i+1], L[2*i]);
      const float d4 = acc[rt][4][j];
      #pragma unroll
      for (int i = 0; i < 8; ++i) u[i] = fmaf(d4, u[2*i+1], u[2*i]);
      const float d3 = acc[rt][3][j];
      #pragma unroll
      for (int i = 0; i < 4; ++i) u[i] = fmaf(d3, u[2*i+1], u[2*i]);
      const float d2 = acc[rt][2][j];
      #pragma unroll
      for (int i = 0; i < 2; ++i) u[i] = fmaf(d2, u[2*i+1], u[2*i]);
      resLo[rt*4+j] = fmaf(acc[rt][1][j], u[1], u[0]);
    }
  #pragma unroll
  for (int c = 0; c < 8; ++c) {
    float4 v = *(const float4*)&coef_lds[tree][32 + c * 4];
    L[c*4+0] = v.x; L[c*4+1] = v.y; L[c*4+2] = v.z; L[c*4+3] = v.w;
  }
  #pragma unroll
  for (int rt = 0; rt < 2; ++rt)
    #pragma unroll
    for (int j = 0; j < 4; ++j) {
      float u[16];
      const float d5 = acc[rt][5][j];
      #pragma unroll
      for (int i = 0; i < 16; ++i) u[i] = fmaf(d5, L[2*i+1], L[2*i]);
      const float d4 = acc[rt][4][j];
      #pragma unroll
      for (int i = 0; i < 8; ++i) u[i] = fmaf(d4, u[2*i+1], u[2*i]);
      const float d3 = acc[rt][3][j];
      #pragma unroll
      for (int i = 0; i < 4; ++i) u[i] = fmaf(d3, u[2*i+1], u[2*i]);
      const float d2 = acc[rt][2][j];
      #pragma unroll
      for (int i = 0; i < 2; ++i) u[i] = fmaf(d2, u[2*i+1], u[2*i]);
      float hi_r = fmaf(acc[rt][1][j], u[1], u[0]);
      float to   = fmaf(acc[rt][0][j], hi_r, resLo[rt*4+j]);
      A2_lds[rt * 16 + g * 4 + j][tree] = f2bf(to);
    }
  __syncthreads();

  // ---- GEMM2: out(32x256) = tree_out_bn(32x64) @ fc_w^T + fc_b ----
  floatx4 acc2[2][4];
  #pragma unroll
  for (int rt = 0; rt < 2; ++rt)
    #pragma unroll
    for (int nt = 0; nt < 4; ++nt) { acc2[rt][nt][0]=0.f; acc2[rt][nt][1]=0.f; acc2[rt][nt][2]=0.f; acc2[rt][nt][3]=0.f; }

  #pragma unroll
  for (int kst = 0; kst < 2; ++kst) {
    short8 a2[2];
    #pragma unroll
    for (int rt = 0; rt < 2; ++rt)
      a2[rt] = *(const short8*)&A2_lds[rt * 16 + tcol][kst * 32 + g * 8];
    #pragma unroll
    for (int nt = 0; nt < 4; ++nt) {
      short8 b2 = *(const short8*)(fcw + (size_t)(w * 64 + nt * 16 + tcol) * 64 + kst * 32 + g * 8);
      #pragma unroll
      for (int rt = 0; rt < 2; ++rt)
        acc2[rt][nt] = __builtin_amdgcn_mfma_f32_16x16x32_bf16(a2[rt], b2, acc2[rt][nt], 0, 0, 0);
    }
  }

  #pragma unroll
  for (int nt = 0; nt < 4; ++nt) {
    const int col = w * 64 + nt * 16 + tcol;
    const float bv = fcb_lds[col];
    #pragma unroll
    for (int rt = 0; rt < 2; ++rt)
      #pragma unroll
      for (int j = 0; j < 4; ++j)
        out[(size_t)(r0 + rt * 16 + g * 4 + j) * 256 + col] = acc2[rt][nt][j] + bv;
  }
}

extern "C" void kernel_launch(void* const* d_in, const int* in_sizes, int n_in,
                              void* d_out, int out_size, void* d_ws, size_t ws_size,
                              hipStream_t stream) {
  const float* x        = (const float*)d_in[0];
  const float* W_dec    = (const float*)d_in[1];
  const float* b_dec    = (const float*)d_in[2];
  const float* leaf     = (const float*)d_in[3];
  const float* bn_gamma = (const float*)d_in[4];
  const float* bn_beta  = (const float*)d_in[5];
  const float* bn_mean  = (const float*)d_in[6];
  const float* bn_var   = (const float*)d_in[7];
  const float* fc_w     = (const float*)d_in[8];
  const float* fc_b     = (const float*)d_in[9];
  float* out = (float*)d_out;

  char* ws = (char*)d_ws;
  unsigned short* Wp  = (unsigned short*)(ws);            // 196608 B
  unsigned short* fcw = (unsigned short*)(ws + 196608);   // 32768 B
  float* coefg = (float*)(ws + 229376);                   // 16384 B
  float* b1    = (float*)(ws + 245760);                   // 1536 B

  // prep work items: 98304 + 16384 + 64 + 384 = 115136 -> 450 blocks
  prep_kernel<<<450, 256, 0, stream>>>(W_dec, b_dec, leaf, bn_gamma, bn_beta,
                                       bn_mean, bn_var, fc_w,
                                       Wp, fcw, coefg, b1);
  node_main<<<1024, 256, 0, stream>>>(x, Wp, fcw, coefg, b1, fc_b, out);
}

// Round 3
// 45.583 us; speedup vs baseline: 1.2436x; 1.2436x over previous
//
#include <hip/hip_runtime.h>
#include <hip/hip_bf16.h>

typedef __attribute__((ext_vector_type(8))) short short8;   // bf16x8 MFMA operand
typedef __attribute__((ext_vector_type(4))) float floatx4;  // f32x4 MFMA accumulator

#define LOG2E 1.4426950408889634f

__device__ __forceinline__ unsigned short f2bf(float f) {
  unsigned int u = __float_as_uint(f);
  u += 0x7FFFu + ((u >> 16) & 1u);   // RNE
  return (unsigned short)(u >> 16);
}

__device__ __forceinline__ unsigned int pk2(float lo, float hi) {
  __hip_bfloat162 h = __float22bfloat162_rn(make_float2(lo, hi)); // v_cvt_pk_bf16_f32
  unsigned int u;
  __builtin_memcpy(&u, &h, 4);
  return u;
}

// ---------------- prep kernel ----------------
// ws layout (bytes):
//   Wp    [384][256] bf16 @ 0        (n' = d*64 + t, pre-scaled by -log2e)
//   fcw   [256][64]  bf16 @ 196608
//   coefg [64][64]   f32  @ 229376   (monomial-basis tree coeffs, BN folded)
//   b1    [384]      f32  @ 245760   (n'-permuted, pre-scaled by -log2e)
__global__ void prep_kernel(const float* __restrict__ W_dec,
                            const float* __restrict__ b_dec,
                            const float* __restrict__ leaf,
                            const float* __restrict__ bn_gamma,
                            const float* __restrict__ bn_beta,
                            const float* __restrict__ bn_mean,
                            const float* __restrict__ bn_var,
                            const float* __restrict__ fc_w,
                            unsigned short* __restrict__ Wp,
                            unsigned short* __restrict__ fcw,
                            float* __restrict__ coefg,
                            float* __restrict__ b1)
{
  int idx = (int)blockIdx.x * 256 + (int)threadIdx.x;
  if (idx < 384 * 256) {
    int np = idx >> 8, k = idx & 255;
    int d = np >> 6, t = np & 63;
    Wp[idx] = f2bf(-LOG2E * W_dec[(t * 6 + d) * 256 + k]);
    return;
  }
  idx -= 384 * 256;
  if (idx < 256 * 64) { fcw[idx] = f2bf(fc_w[idx]); return; }
  idx -= 256 * 64;
  if (idx < 64) {
    // Mobius transform: leaf values -> monomial coefficients over (dec5..dec0).
    const int t = idx;
    float c[64];
    #pragma unroll
    for (int i = 0; i < 64; ++i) c[i] = leaf[t * 64 + i];
    #pragma unroll
    for (int p = 0; p < 6; ++p) {
      const int s = 1 << p;
      #pragma unroll
      for (int i = 0; i < 64; ++i)
        if ((i & s) == 0) c[i + s] -= c[i];
    }
    float sbv = bn_gamma[t] * rsqrtf(bn_var[t] + 1e-5f);
    float obv = bn_beta[t] - bn_mean[t] * sbv;
    #pragma unroll
    for (int i = 0; i < 64; ++i) c[i] *= sbv;
    c[0] += obv;
    #pragma unroll
    for (int i = 0; i < 64; ++i) coefg[t * 64 + i] = c[i];
    return;
  }
  idx -= 64;
  if (idx < 384) {
    int t = idx / 6, d = idx % 6;
    b1[d * 64 + t] = -LOG2E * b_dec[idx];
  }
}

// ---------------- main fused kernel ----------------
// grid 1024 x 256 threads; BM=32 rows/block; 4 waves, wave w owns trees [16w,16w+16)
// LDS 36 KB -> 4 blocks/CU. x staged to LDS as bf16; A2 aliases the x region.
__global__ __launch_bounds__(256, 4)
void node_main(const float* __restrict__ x,
               const unsigned short* __restrict__ Wp,
               const unsigned short* __restrict__ fcw,
               const float* __restrict__ coefg,
               const float* __restrict__ b1g,
               const float* __restrict__ fc_b,
               float* __restrict__ out)
{
  // smem layout:
  //   [0, 16896)      xbf [32][264] bf16   (pad +8 shorts -> 2-way free frag reads)
  //                   A2  [32][72]  bf16   (ALIASES xbf; written after GEMM1 barrier)
  //   [16896, 34304)  coef[64][68]  f32    (pad +4 -> 2-way)
  //   [34304, 35840)  b1  [384]     f32
  //   [35840, 36864)  fcb [256]     f32
  __shared__ __align__(16) char smem[36864];
  unsigned short (*xbf)[264] = (unsigned short (*)[264])smem;
  unsigned short (*A2)[72]   = (unsigned short (*)[72])smem;
  float (*coef_lds)[68]      = (float (*)[68])(smem + 16896);
  float* b1_lds              = (float*)(smem + 34304);
  float* fcb_lds             = (float*)(smem + 35840);

  const int tid  = (int)threadIdx.x;
  const int lane = tid & 63;
  const int w    = tid >> 6;      // wave 0..3
  const int tcol = lane & 15;
  const int g    = lane >> 4;
  const int r0   = (int)blockIdx.x * 32;

  // ---- stage: x tile (32x256 f32) -> bf16 xbf; coef; b1; fcb ----
  {
    const float4* xs = (const float4*)(x + (size_t)r0 * 256);
    #pragma unroll
    for (int i = 0; i < 8; ++i) {
      int f = tid + 256 * i;            // float4 index 0..2047, coalesced
      float4 v = xs[f];
      int row = f >> 6, c4 = f & 63;
      unsigned int* p = (unsigned int*)&xbf[row][c4 * 4];
      p[0] = pk2(v.x, v.y);
      p[1] = pk2(v.z, v.w);
    }
    #pragma unroll
    for (int i = 0; i < 4; ++i) {
      int f = tid + 256 * i;            // float4 index 0..1023
      int t = f >> 4, c4 = f & 15;
      *(float4*)&coef_lds[t][c4 * 4] = ((const float4*)coefg)[f];
    }
    b1_lds[tid] = b1g[tid];
    if (tid < 128) b1_lds[256 + tid] = b1g[256 + tid];
    fcb_lds[tid] = fc_b[tid];
  }
  __syncthreads();

  // ---- GEMM1: acc[rt][d] = x(32x256) @ Wp-slice; A from LDS, B from global (L2-hot) ----
  floatx4 acc[2][6];
  #pragma unroll
  for (int rt = 0; rt < 2; ++rt)
    #pragma unroll
    for (int d = 0; d < 6; ++d) { acc[rt][d][0]=0.f; acc[rt][d][1]=0.f; acc[rt][d][2]=0.f; acc[rt][d][3]=0.f; }

  const unsigned short* Bb = Wp + (size_t)(w * 16 + tcol) * 256 + g * 8;

  #pragma unroll
  for (int kp = 0; kp < 8; ++kp) {
    short8 b[6];
    #pragma unroll
    for (int d = 0; d < 6; ++d) b[d] = *(const short8*)(Bb + d * 16384 + kp * 32);
    short8 a0 = *(const short8*)&xbf[tcol][kp * 32 + g * 8];
    short8 a1 = *(const short8*)&xbf[16 + tcol][kp * 32 + g * 8];
    #pragma unroll
    for (int d = 0; d < 6; ++d) {
      acc[0][d] = __builtin_amdgcn_mfma_f32_16x16x32_bf16(a0, b[d], acc[0][d], 0, 0, 0);
      acc[1][d] = __builtin_amdgcn_mfma_f32_16x16x32_bf16(a1, b[d], acc[1][d], 0, 0, 0);
    }
  }
  __syncthreads();   // all x-reads done -> A2 may now alias; coef/b1 visible

  // ---- phase 2: sigmoid + monomial-basis tree eval (63 fma), BN pre-folded ----
  const int tree = w * 16 + tcol;   // lane's tree; its 8 rows: rt*16 + g*4 + j
  float bp[6];
  #pragma unroll
  for (int d = 0; d < 6; ++d) bp[d] = b1_lds[d * 64 + tree];

  #pragma unroll
  for (int rt = 0; rt < 2; ++rt)
    #pragma unroll
    for (int d = 0; d < 6; ++d)
      #pragma unroll
      for (int j = 0; j < 4; ++j) {
        float z = acc[rt][d][j] + bp[d];
        acc[rt][d][j] = __builtin_amdgcn_rcpf(1.0f + __builtin_amdgcn_exp2f(z));
      }

  float L[32], resLo[8];
  #pragma unroll
  for (int c = 0; c < 8; ++c) {
    float4 v = *(const float4*)&coef_lds[tree][c * 4];
    L[c*4+0] = v.x; L[c*4+1] = v.y; L[c*4+2] = v.z; L[c*4+3] = v.w;
  }
  #pragma unroll
  for (int rt = 0; rt < 2; ++rt)
    #pragma unroll
    for (int j = 0; j < 4; ++j) {
      float u[16];
      const float d5 = acc[rt][5][j];
      #pragma unroll
      for (int i = 0; i < 16; ++i) u[i] = fmaf(d5, L[2*i+1], L[2*i]);
      const float d4 = acc[rt][4][j];
      #pragma unroll
      for (int i = 0; i < 8; ++i) u[i] = fmaf(d4, u[2*i+1], u[2*i]);
      const float d3 = acc[rt][3][j];
      #pragma unroll
      for (int i = 0; i < 4; ++i) u[i] = fmaf(d3, u[2*i+1], u[2*i]);
      const float d2 = acc[rt][2][j];
      #pragma unroll
      for (int i = 0; i < 2; ++i) u[i] = fmaf(d2, u[2*i+1], u[2*i]);
      resLo[rt*4+j] = fmaf(acc[rt][1][j], u[1], u[0]);
    }
  #pragma unroll
  for (int c = 0; c < 8; ++c) {
    float4 v = *(const float4*)&coef_lds[tree][32 + c * 4];
    L[c*4+0] = v.x; L[c*4+1] = v.y; L[c*4+2] = v.z; L[c*4+3] = v.w;
  }
  #pragma unroll
  for (int rt = 0; rt < 2; ++rt)
    #pragma unroll
    for (int j = 0; j < 4; ++j) {
      float u[16];
      const float d5 = acc[rt][5][j];
      #pragma unroll
      for (int i = 0; i < 16; ++i) u[i] = fmaf(d5, L[2*i+1], L[2*i]);
      const float d4 = acc[rt][4][j];
      #pragma unroll
      for (int i = 0; i < 8; ++i) u[i] = fmaf(d4, u[2*i+1], u[2*i]);
      const float d3 = acc[rt][3][j];
      #pragma unroll
      for (int i = 0; i < 4; ++i) u[i] = fmaf(d3, u[2*i+1], u[2*i]);
      const float d2 = acc[rt][2][j];
      #pragma unroll
      for (int i = 0; i < 2; ++i) u[i] = fmaf(d2, u[2*i+1], u[2*i]);
      float hi_r = fmaf(acc[rt][1][j], u[1], u[0]);
      float to   = fmaf(acc[rt][0][j], hi_r, resLo[rt*4+j]);
      A2[rt * 16 + g * 4 + j][tree] = f2bf(to);
    }
  __syncthreads();

  // ---- GEMM2: out(32x256) = tree_out_bn(32x64) @ fc_w^T + fc_b ----
  floatx4 acc2[2][4];
  #pragma unroll
  for (int rt = 0; rt < 2; ++rt)
    #pragma unroll
    for (int nt = 0; nt < 4; ++nt) { acc2[rt][nt][0]=0.f; acc2[rt][nt][1]=0.f; acc2[rt][nt][2]=0.f; acc2[rt][nt][3]=0.f; }

  #pragma unroll
  for (int kst = 0; kst < 2; ++kst) {
    short8 a2[2];
    #pragma unroll
    for (int rt = 0; rt < 2; ++rt)
      a2[rt] = *(const short8*)&A2[rt * 16 + tcol][kst * 32 + g * 8];
    #pragma unroll
    for (int nt = 0; nt < 4; ++nt) {
      short8 b2 = *(const short8*)(fcw + (size_t)(w * 64 + nt * 16 + tcol) * 64 + kst * 32 + g * 8);
      #pragma unroll
      for (int rt = 0; rt < 2; ++rt)
        acc2[rt][nt] = __builtin_amdgcn_mfma_f32_16x16x32_bf16(a2[rt], b2, acc2[rt][nt], 0, 0, 0);
    }
  }

  #pragma unroll
  for (int nt = 0; nt < 4; ++nt) {
    const int col = w * 64 + nt * 16 + tcol;
    const float bv = fcb_lds[col];
    #pragma unroll
    for (int rt = 0; rt < 2; ++rt)
      #pragma unroll
      for (int j = 0; j < 4; ++j)
        out[(size_t)(r0 + rt * 16 + g * 4 + j) * 256 + col] = acc2[rt][nt][j] + bv;
  }
}

extern "C" void kernel_launch(void* const* d_in, const int* in_sizes, int n_in,
                              void* d_out, int out_size, void* d_ws, size_t ws_size,
                              hipStream_t stream) {
  const float* x        = (const float*)d_in[0];
  const float* W_dec    = (const float*)d_in[1];
  const float* b_dec    = (const float*)d_in[2];
  const float* leaf     = (const float*)d_in[3];
  const float* bn_gamma = (const float*)d_in[4];
  const float* bn_beta  = (const float*)d_in[5];
  const float* bn_mean  = (const float*)d_in[6];
  const float* bn_var   = (const float*)d_in[7];
  const float* fc_w     = (const float*)d_in[8];
  const float* fc_b     = (const float*)d_in[9];
  float* out = (float*)d_out;

  char* ws = (char*)d_ws;
  unsigned short* Wp  = (unsigned short*)(ws);            // 196608 B
  unsigned short* fcw = (unsigned short*)(ws + 196608);   // 32768 B
  float* coefg = (float*)(ws + 229376);                   // 16384 B
  float* b1    = (float*)(ws + 245760);                   // 1536 B

  // prep work items: 98304 + 16384 + 64 + 384 = 115136 -> 450 blocks
  prep_kernel<<<450, 256, 0, stream>>>(W_dec, b_dec, leaf, bn_gamma, bn_beta,
                                       bn_mean, bn_var, fc_w,
                                       Wp, fcw, coefg, b1);
  node_main<<<1024, 256, 0, stream>>>(x, Wp, fcw, coefg, b1, fc_b, out);
}